// Round 3
// baseline (188.958 us; speedup 1.0000x reference)
//
#include <hip/hip_runtime.h>
#include <hip/hip_bf16.h>
#include <math.h>

// Problem constants: B=8, S=1024, D=768, H=12, DH=64. fp32 in, fp32 out.
constexpr int Bn = 8, Sn = 1024, Dn = 768, Hn = 12, DHn = 64;
constexpr int QKV_ELEMS = Bn * Hn * Sn * DHn;  // 6291456
// sqrt(log2(e)/sqrt(DH)) — folded into Wq,bq,Wk,bk so scores come out
// pre-scaled for exp2. 0.42466086^2 = 0.18033688 = 0.125*log2(e).
constexpr float SQC = 0.42466086f;

typedef __attribute__((ext_vector_type(8))) short bf16x8;  // 8 bf16 = 4 VGPRs
typedef __attribute__((ext_vector_type(4))) float f32x4;   // MFMA 16x16 C/D

// pack 2 floats -> 2 bf16 (round-nearest) in 3 VALU ops: add, add, perm
__device__ __forceinline__ unsigned int pk2bf(float a, float b) {
    union { float f; unsigned u; } ca{a}, cb{b};
    return __builtin_amdgcn_perm(cb.u + 0x8000u, ca.u + 0x8000u, 0x07060302u);
}

// Build a W^T A/B-fragment (rows e, k = d) straight from fp32 W[h][d][e]:
// element j of chunk kc = W[d = kc*32 + quad*8 + j][e] * sc.
__device__ __forceinline__ bf16x8 wfrag(const float* __restrict__ W,
                                        int e, int kc, int quad, float sc) {
    const float* p = W + (size_t)(kc * 32 + quad * 8) * 64 + e;
    unsigned int tmp[4];
    #pragma unroll
    for (int j = 0; j < 4; j++)
        tmp[j] = pk2bf(p[(2 * j) * 64] * sc, p[(2 * j + 1) * 64] * sc);
    return *(bf16x8*)tmp;
}

// ---------------------------------------------------------------------------
// Kernel 1 (proj): K and V. Grid re-swizzled so ALL 16 tiles of a given bh
// run on the bh's consumer XCD (blk&7 == bh/12) -> k_ws/vt_ws for that head
// are written into (and stay in) the same XCD L2 the attn kernel reads from.
// ---------------------------------------------------------------------------
__global__ __launch_bounds__(256) void proj_kernel(
    const float* __restrict__ x,
    const float* __restrict__ Wk, const float* __restrict__ bk,
    const float* __restrict__ Wv, const float* __restrict__ bv,
    unsigned short* __restrict__ k_ws, unsigned short* __restrict__ vt_ws)
{
    __shared__ unsigned short Xs[64 * 72];   // [s][d] bf16
    __shared__ unsigned short ObK[64 * 72];  // [s][e]
    __shared__ unsigned short ObV[64 * 72];  // [e][s]

    const int blk  = blockIdx.x;        // 1536 = 8 xcd * (12 bh' * 16 tile)
    const int xcd  = blk & 7;
    const int g    = blk >> 3;          // 0..191
    const int bh   = xcd * 12 + (g % 12);
    const int tile = g / 12;            // 0..15
    const int h    = bh % Hn;
    const int b    = bh / Hn;
    const int t    = threadIdx.x;
    const int w    = t >> 6;            // wave 0..3 -> e-strip w*16
    const int lane = t & 63;
    const int l    = lane & 15;
    const int quad = lane >> 4;
    const int sr   = t >> 2;            // staging row
    const int sc0  = (t & 3) * 16;      // staging col base
    const int s0   = tile * 64;

    {   // stage X tile [64 s][64 d] fp32 -> bf16
        const float* xrow = x + ((size_t)(b * Sn + s0 + sr) * Dn + h * 64 + sc0);
        unsigned int tmp[8];
        #pragma unroll
        for (int q4 = 0; q4 < 4; q4++) {
            float4 v = ((const float4*)xrow)[q4];
            tmp[2 * q4 + 0] = pk2bf(v.x, v.y);
            tmp[2 * q4 + 1] = pk2bf(v.z, v.w);
        }
        *(uint4*)&Xs[sr * 72 + sc0]     = ((uint4*)tmp)[0];
        *(uint4*)&Xs[sr * 72 + sc0 + 8] = ((uint4*)tmp)[1];
    }

    // W^T fragments, rows e = w*16 + l, inline from fp32 (L2-hot)
    const int e = w * 16 + l;
    bf16x8 wk[2], wv[2];
    #pragma unroll
    for (int kc = 0; kc < 2; kc++) {
        wk[kc] = wfrag(Wk + (size_t)h * 4096, e, kc, quad, SQC);
        wv[kc] = wfrag(Wv + (size_t)h * 4096, e, kc, quad, 1.0f);
    }
    float4 bkv = *(const float4*)(bk + h * 64 + w * 16 + quad * 4);
    bkv.x *= SQC; bkv.y *= SQC; bkv.z *= SQC; bkv.w *= SQC;
    const float bvl = bv[h * 64 + e];

    __syncthreads();   // Xs ready

    bf16x8 xf[4][2];
    #pragma unroll
    for (int nt = 0; nt < 4; nt++)
        #pragma unroll
        for (int kc = 0; kc < 2; kc++)
            xf[nt][kc] = *(bf16x8*)&Xs[(nt * 16 + l) * 72 + kc * 32 + quad * 8];

    #pragma unroll
    for (int nt = 0; nt < 4; nt++) {
        // K: D[m=e][n=key] = Wk^T . X^T -> ObK[key][e] packed b64
        f32x4 ak = (f32x4){bkv.x, bkv.y, bkv.z, bkv.w};
        ak = __builtin_amdgcn_mfma_f32_16x16x32_bf16(wk[0], xf[nt][0], ak, 0, 0, 0);
        ak = __builtin_amdgcn_mfma_f32_16x16x32_bf16(wk[1], xf[nt][1], ak, 0, 0, 0);
        *(uint2*)&ObK[(nt * 16 + l) * 72 + w * 16 + quad * 4] =
            make_uint2(pk2bf(ak[0], ak[1]), pk2bf(ak[2], ak[3]));
        // V: D[m=key][n=e] = X . Wv^T -> ObV[e][key] packed b64
        f32x4 av = (f32x4){bvl, bvl, bvl, bvl};
        av = __builtin_amdgcn_mfma_f32_16x16x32_bf16(xf[nt][0], wv[0], av, 0, 0, 0);
        av = __builtin_amdgcn_mfma_f32_16x16x32_bf16(xf[nt][1], wv[1], av, 0, 0, 0);
        *(uint2*)&ObV[(w * 16 + l) * 72 + nt * 16 + quad * 4] =
            make_uint2(pk2bf(av[0], av[1]), pk2bf(av[2], av[3]));
    }
    __syncthreads();   // ObK/ObV ready

    {   // coalesced b128 global stores
        uint4 a  = *(uint4*)&ObK[sr * 72 + sc0];
        uint4 b4 = *(uint4*)&ObK[sr * 72 + sc0 + 8];
        unsigned short* dst = k_ws + (size_t)(bh * Sn + s0 + sr) * 64 + sc0;
        ((uint4*)dst)[0] = a;
        *(uint4*)(dst + 8) = b4;
    }
    {
        uint4 a  = *(uint4*)&ObV[sr * 72 + sc0];
        uint4 b4 = *(uint4*)&ObV[sr * 72 + sc0 + 8];
        unsigned short* dst = vt_ws + (size_t)bh * 64 * Sn + (size_t)sr * Sn + s0 + sc0;
        ((uint4*)dst)[0] = a;
        *(uint4*)(dst + 8) = b4;
    }
}

// ---------------------------------------------------------------------------
// Kernel 2 (attn): fused Q-projection + flash attention, BARRIER-FREE.
// K/V MFMA fragments are loaded directly from global (L2-resident on this
// XCD thanks to the proj-grid swizzle) — no Ks/Vt LDS staging, no
// __syncthreads anywhere. The only LDS use is the per-wave P/Q roundtrip
// (Pw), which is same-wave in-order DS traffic guarded by lgkmcnt(0).
// All 16 K/V loads issue at the iter top; the compiler's counted vmcnt
// waits let V loads stay in flight through QK^T + softmax.
// ---------------------------------------------------------------------------
__global__ __launch_bounds__(256, 3) void attn_kernel(
    const float* __restrict__ x,
    const float* __restrict__ Wq, const float* __restrict__ bq,
    const unsigned short* __restrict__ k_ws,
    const unsigned short* __restrict__ vt_ws,
    float* __restrict__ out)
{
    __shared__ unsigned short Pws[4 * 32 * 72];  // per-wave P / Q staging only

    const int blk = blockIdx.x;    // 768 = 8 XCD * 12 bh * 8 qt
    const int xcd = blk & 7;
    const int idx = blk >> 3;      // 0..95
    const int bh  = xcd * 12 + (idx % 12);
    const int qt  = idx / 12;      // 0..7 (128-query tiles)
    const int t    = threadIdx.x;
    const int w    = t >> 6;
    const int lane = t & 63;
    const int l    = lane & 15;
    const int quad = lane >> 4;

    const int b = bh / Hn, h = bh % Hn;
    const size_t base  = (size_t)bh * Sn * 64;   // k_ws [bh][s][e]
    const size_t vbase = (size_t)bh * 64 * Sn;   // vt_ws [bh][e][s]
    unsigned short* Pw = Pws + w * 32 * 72;

    // ---- Q-projection prologue: 32 queries per wave ----
    bf16x8 qf[2][2];
    {
        bf16x8 xq[2][2];
        #pragma unroll
        for (int st = 0; st < 2; st++) {
            const float* xp = x + ((size_t)(b * Sn + qt * 128 + w * 32 + st * 16 + l) * Dn
                                   + h * 64 + quad * 8);
            #pragma unroll
            for (int kc = 0; kc < 2; kc++) {
                float4 v0 = *(const float4*)(xp + kc * 32);
                float4 v1 = *(const float4*)(xp + kc * 32 + 4);
                unsigned int tmp[4] = {pk2bf(v0.x, v0.y), pk2bf(v0.z, v0.w),
                                       pk2bf(v1.x, v1.y), pk2bf(v1.z, v1.w)};
                xq[st][kc] = *(bf16x8*)tmp;
            }
        }
        #pragma unroll
        for (int nt = 0; nt < 4; nt++) {
            bf16x8 wa0 = wfrag(Wq + (size_t)h * 4096, nt * 16 + l, 0, quad, SQC);
            bf16x8 wa1 = wfrag(Wq + (size_t)h * 4096, nt * 16 + l, 1, quad, SQC);
            float4 bqv = *(const float4*)(bq + h * 64 + nt * 16 + quad * 4);
            #pragma unroll
            for (int st = 0; st < 2; st++) {
                f32x4 acc = (f32x4){bqv.x * SQC, bqv.y * SQC, bqv.z * SQC, bqv.w * SQC};
                acc = __builtin_amdgcn_mfma_f32_16x16x32_bf16(wa0, xq[st][0], acc, 0, 0, 0);
                acc = __builtin_amdgcn_mfma_f32_16x16x32_bf16(wa1, xq[st][1], acc, 0, 0, 0);
                *(uint2*)&Pw[(st * 16 + l) * 72 + nt * 16 + quad * 4] =
                    make_uint2(pk2bf(acc[0], acc[1]), pk2bf(acc[2], acc[3]));
            }
        }
        __asm__ volatile("s_waitcnt lgkmcnt(0)" ::: "memory");
        #pragma unroll
        for (int st = 0; st < 2; st++) {
            qf[st][0] = *(bf16x8*)&Pw[(st * 16 + l) * 72 + quad * 8];
            qf[st][1] = *(bf16x8*)&Pw[(st * 16 + l) * 72 + 32 + quad * 8];
        }
    }

    f32x4 Oa[2][4];
    #pragma unroll
    for (int st = 0; st < 2; st++)
        #pragma unroll
        for (int nt = 0; nt < 4; nt++) Oa[st][nt] = (f32x4){0.f, 0.f, 0.f, 0.f};
    float ps[2] = {0.f, 0.f};

    for (int kt = 0; kt < 16; kt++) {
        // ---- all K and V fragment loads issue here (L2-hot, no barrier) ----
        bf16x8 kf[4][2], vf[4][2];
        #pragma unroll
        for (int nt = 0; nt < 4; nt++) {
            const unsigned short* kp =
                k_ws + base + (size_t)(kt * 64 + nt * 16 + l) * 64 + quad * 8;
            kf[nt][0] = *(const bf16x8*)kp;
            kf[nt][1] = *(const bf16x8*)(kp + 32);
            const unsigned short* vp =
                vt_ws + vbase + (size_t)(nt * 16 + l) * Sn + kt * 64 + quad * 8;
            vf[nt][0] = *(const bf16x8*)vp;
            vf[nt][1] = *(const bf16x8*)(vp + 32);
        }

        // ---- S^T per key-strip nt: A = K rows, B = Q; exp2 + packed P ----
        #pragma unroll
        for (int nt = 0; nt < 4; nt++) {
            #pragma unroll
            for (int st = 0; st < 2; st++) {
                f32x4 s = (f32x4){0.f, 0.f, 0.f, 0.f};
                s = __builtin_amdgcn_mfma_f32_16x16x32_bf16(kf[nt][0], qf[st][0], s, 0, 0, 0);
                s = __builtin_amdgcn_mfma_f32_16x16x32_bf16(kf[nt][1], qf[st][1], s, 0, 0, 0);
                float p0 = exp2f(s[0]), p1 = exp2f(s[1]);
                float p2 = exp2f(s[2]), p3 = exp2f(s[3]);
                ps[st] += (p0 + p1) + (p2 + p3);
                *(uint2*)&Pw[(st * 16 + l) * 72 + nt * 16 + quad * 4] =
                    make_uint2(pk2bf(p0, p1), pk2bf(p2, p3));
            }
        }
        __asm__ volatile("s_waitcnt lgkmcnt(0)" ::: "memory");

        bf16x8 pf[2][2];
        #pragma unroll
        for (int st = 0; st < 2; st++) {
            pf[st][0] = *(bf16x8*)&Pw[(st * 16 + l) * 72 + quad * 8];
            pf[st][1] = *(bf16x8*)&Pw[(st * 16 + l) * 72 + 32 + quad * 8];
        }

        // ---- O += P.V : B = V^T fragments straight from registers ----
        #pragma unroll
        for (int nt = 0; nt < 4; nt++) {
            #pragma unroll
            for (int st = 0; st < 2; st++) {
                Oa[st][nt] = __builtin_amdgcn_mfma_f32_16x16x32_bf16(pf[st][0], vf[nt][0], Oa[st][nt], 0, 0, 0);
                Oa[st][nt] = __builtin_amdgcn_mfma_f32_16x16x32_bf16(pf[st][1], vf[nt][1], Oa[st][nt], 0, 0, 0);
            }
        }
    }

    // fold partial sums across the 4 quads (keys), fetch per-query inv
    #pragma unroll
    for (int st = 0; st < 2; st++) {
        ps[st] += __shfl_xor(ps[st], 16, 64);
        ps[st] += __shfl_xor(ps[st], 32, 64);
    }
    #pragma unroll
    for (int st = 0; st < 2; st++) {
        float inv[4];
        #pragma unroll
        for (int r = 0; r < 4; r++) inv[r] = 1.0f / __shfl(ps[st], quad * 4 + r, 64);
        #pragma unroll
        for (int nt = 0; nt < 4; nt++)
            #pragma unroll
            for (int r = 0; r < 4; r++) {
                int srow = qt * 128 + w * 32 + st * 16 + quad * 4 + r;
                out[(size_t)(b * Sn + srow) * Dn + h * 64 + nt * 16 + l] = Oa[st][nt][r] * inv[r];
            }
    }
}

// ---------------------------------------------------------------------------
extern "C" void kernel_launch(void* const* d_in, const int* in_sizes, int n_in,
                              void* d_out, int out_size, void* d_ws, size_t ws_size,
                              hipStream_t stream) {
    const float* x  = (const float*)d_in[0];
    const float* Wq = (const float*)d_in[1];
    const float* bq = (const float*)d_in[2];
    const float* Wk = (const float*)d_in[3];
    const float* bk = (const float*)d_in[4];
    const float* Wv = (const float*)d_in[5];
    const float* bv = (const float*)d_in[6];
    float* out = (float*)d_out;

    unsigned short* k_ws  = (unsigned short*)d_ws;
    unsigned short* vt_ws = k_ws + QKV_ELEMS;

    hipLaunchKernelGGL(proj_kernel, dim3(Bn * Hn * 16), dim3(256), 0, stream,
                       x, Wk, bk, Wv, bv, k_ws, vt_ws);
    hipLaunchKernelGGL(attn_kernel, dim3(Bn * Hn * 8), dim3(256), 0, stream,
                       x, Wq, bq, k_ws, vt_ws, out);
}

// Round 5
// 144.997 us; speedup vs baseline: 1.3032x; 1.3032x over previous
//
#include <hip/hip_runtime.h>
#include <hip/hip_bf16.h>
#include <math.h>

// Problem constants: B=8, S=1024, D=768, H=12, DH=64. fp32 in, fp32 out.
constexpr int Bn = 8, Sn = 1024, Dn = 768, Hn = 12, DHn = 64;
constexpr int QKV_ELEMS = Bn * Hn * Sn * DHn;  // 6291456
// sqrt(log2(e)/sqrt(DH)) — folded into Wq,bq,Wk,bk so scores come out
// pre-scaled for exp2. 0.42466086^2 = 0.18033688 = 0.125*log2(e).
constexpr float SQC = 0.42466086f;

typedef __attribute__((ext_vector_type(8))) short bf16x8;  // 8 bf16 = 4 VGPRs
typedef __attribute__((ext_vector_type(4))) float f32x4;   // MFMA 16x16 C/D

// pack 2 floats -> 2 bf16 (round-nearest) in 3 VALU ops: add, add, perm
__device__ __forceinline__ unsigned int pk2bf(float a, float b) {
    union { float f; unsigned u; } ca{a}, cb{b};
    return __builtin_amdgcn_perm(cb.u + 0x8000u, ca.u + 0x8000u, 0x07060302u);
}

// Quad-redistribution (UNAMBIGUOUS primitives: shfl_xor + cndmask).
// In : X holds value t_q at quad q (pairs at keys 16*ntLo+4q+2m),
//      Y holds u_q               (pairs at keys 16*ntHi+4q+2m)
// Out: X = [t0,t2,u0,u2] per dst quad  -> B-frag word w=m   (keys 8q'+2m)
//      Y = [t1,t3,u1,u3] per dst quad  -> B-frag word w=m+2 (keys 8q'+4+2m)
// step1 (lane bit5): X=[t0,t1,u0,u1], Y=[t2,t3,u2,u3]
// step2 (lane bit4): X=[t0,t2,u0,u2], Y=[t1,t3,u1,u3]   (element-traced)
__device__ __forceinline__ void quad_net(unsigned &X, unsigned &Y, int quad) {
    unsigned v = (quad >= 2) ? X : Y;        // [u0,u1,t2,t3]
    v = __shfl_xor(v, 32, 64);               // [t2,t3,u0,u1]
    unsigned X1 = (quad >= 2) ? v : X;       // [t0,t1,u0,u1]
    unsigned Y1 = (quad >= 2) ? Y : v;       // [t2,t3,u2,u3]
    unsigned w2 = (quad & 1) ? X1 : Y1;      // [t2,t1,u2,u1]
    w2 = __shfl_xor(w2, 16, 64);             // [t1,t2,u1,u2]
    X = (quad & 1) ? w2 : X1;                // [t0,t2,u0,u2]
    Y = (quad & 1) ? Y1 : w2;                // [t1,t3,u1,u3]
}

// Build a W^T A/B-fragment (rows e, k = d) straight from fp32 W[h][d][e]:
// element j of chunk kc = W[d = kc*32 + quad*8 + j][e] * sc.
__device__ __forceinline__ bf16x8 wfrag(const float* __restrict__ W,
                                        int e, int kc, int quad, float sc) {
    const float* p = W + (size_t)(kc * 32 + quad * 8) * 64 + e;
    unsigned int tmp[4];
    #pragma unroll
    for (int j = 0; j < 4; j++)
        tmp[j] = pk2bf(p[(2 * j) * 64] * sc, p[(2 * j + 1) * 64] * sc);
    return *(bf16x8*)tmp;
}

// ---------------------------------------------------------------------------
// Kernel 1 (proj): K and V. Grid swizzled so ALL 16 tiles of a given bh run
// on the bh's consumer XCD (blk&7 == bh/12) -> k_ws/vt_ws for that head are
// written into (and stay in) the same XCD L2 the attn kernel reads from.
// (Verified passing in round 3.)
// ---------------------------------------------------------------------------
__global__ __launch_bounds__(256) void proj_kernel(
    const float* __restrict__ x,
    const float* __restrict__ Wk, const float* __restrict__ bk,
    const float* __restrict__ Wv, const float* __restrict__ bv,
    unsigned short* __restrict__ k_ws, unsigned short* __restrict__ vt_ws)
{
    __shared__ unsigned short Xs[64 * 72];   // [s][d] bf16
    __shared__ unsigned short ObK[64 * 72];  // [s][e]
    __shared__ unsigned short ObV[64 * 72];  // [e][s]

    const int blk  = blockIdx.x;        // 1536 = 8 xcd * (12 bh' * 16 tile)
    const int xcd  = blk & 7;
    const int g    = blk >> 3;          // 0..191
    const int bh   = xcd * 12 + (g % 12);
    const int tile = g / 12;            // 0..15
    const int h    = bh % Hn;
    const int b    = bh / Hn;
    const int t    = threadIdx.x;
    const int w    = t >> 6;            // wave 0..3 -> e-strip w*16
    const int lane = t & 63;
    const int l    = lane & 15;
    const int quad = lane >> 4;
    const int sr   = t >> 2;            // staging row
    const int sc0  = (t & 3) * 16;      // staging col base
    const int s0   = tile * 64;

    {   // stage X tile [64 s][64 d] fp32 -> bf16
        const float* xrow = x + ((size_t)(b * Sn + s0 + sr) * Dn + h * 64 + sc0);
        unsigned int tmp[8];
        #pragma unroll
        for (int q4 = 0; q4 < 4; q4++) {
            float4 v = ((const float4*)xrow)[q4];
            tmp[2 * q4 + 0] = pk2bf(v.x, v.y);
            tmp[2 * q4 + 1] = pk2bf(v.z, v.w);
        }
        *(uint4*)&Xs[sr * 72 + sc0]     = ((uint4*)tmp)[0];
        *(uint4*)&Xs[sr * 72 + sc0 + 8] = ((uint4*)tmp)[1];
    }

    // W^T fragments, rows e = w*16 + l, inline from fp32 (L2-hot)
    const int e = w * 16 + l;
    bf16x8 wk[2], wv[2];
    #pragma unroll
    for (int kc = 0; kc < 2; kc++) {
        wk[kc] = wfrag(Wk + (size_t)h * 4096, e, kc, quad, SQC);
        wv[kc] = wfrag(Wv + (size_t)h * 4096, e, kc, quad, 1.0f);
    }
    float4 bkv = *(const float4*)(bk + h * 64 + w * 16 + quad * 4);
    bkv.x *= SQC; bkv.y *= SQC; bkv.z *= SQC; bkv.w *= SQC;
    const float bvl = bv[h * 64 + e];

    __syncthreads();   // Xs ready

    bf16x8 xf[4][2];
    #pragma unroll
    for (int nt = 0; nt < 4; nt++)
        #pragma unroll
        for (int kc = 0; kc < 2; kc++)
            xf[nt][kc] = *(bf16x8*)&Xs[(nt * 16 + l) * 72 + kc * 32 + quad * 8];

    #pragma unroll
    for (int nt = 0; nt < 4; nt++) {
        // K: D[m=e][n=key] = Wk^T . X^T -> ObK[key][e] packed b64
        f32x4 ak = (f32x4){bkv.x, bkv.y, bkv.z, bkv.w};
        ak = __builtin_amdgcn_mfma_f32_16x16x32_bf16(wk[0], xf[nt][0], ak, 0, 0, 0);
        ak = __builtin_amdgcn_mfma_f32_16x16x32_bf16(wk[1], xf[nt][1], ak, 0, 0, 0);
        *(uint2*)&ObK[(nt * 16 + l) * 72 + w * 16 + quad * 4] =
            make_uint2(pk2bf(ak[0], ak[1]), pk2bf(ak[2], ak[3]));
        // V: D[m=key][n=e] = X . Wv^T -> ObV[e][key] packed b64
        f32x4 av = (f32x4){bvl, bvl, bvl, bvl};
        av = __builtin_amdgcn_mfma_f32_16x16x32_bf16(xf[nt][0], wv[0], av, 0, 0, 0);
        av = __builtin_amdgcn_mfma_f32_16x16x32_bf16(xf[nt][1], wv[1], av, 0, 0, 0);
        *(uint2*)&ObV[(w * 16 + l) * 72 + nt * 16 + quad * 4] =
            make_uint2(pk2bf(av[0], av[1]), pk2bf(av[2], av[3]));
    }
    __syncthreads();   // ObK/ObV ready

    {   // coalesced b128 global stores
        uint4 a  = *(uint4*)&ObK[sr * 72 + sc0];
        uint4 b4 = *(uint4*)&ObK[sr * 72 + sc0 + 8];
        unsigned short* dst = k_ws + (size_t)(bh * Sn + s0 + sr) * 64 + sc0;
        ((uint4*)dst)[0] = a;
        *(uint4*)(dst + 8) = b4;
    }
    {
        uint4 a  = *(uint4*)&ObV[sr * 72 + sc0];
        uint4 b4 = *(uint4*)&ObV[sr * 72 + sc0 + 8];
        unsigned short* dst = vt_ws + (size_t)bh * 64 * Sn + (size_t)sr * Sn + s0 + sc0;
        ((uint4*)dst)[0] = a;
        *(uint4*)(dst + 8) = b4;
    }
}

// ---------------------------------------------------------------------------
// Kernel 2 (attn): round-0 verified structure (fused Q-proj + flash attn,
// LDS-staged K/V, register double-buffer, 2 barriers/iter) with the P/Q LDS
// transpose roundtrip replaced by the shfl_xor quad-redistribution, and PV
// computed as O^T = V^T.P (operand swap) so query stays lane-resident:
// per-lane normalizer, float4 epilogue stores. No Pws buffer, no lgkmcnt(0)
// drains in the loop.
// ---------------------------------------------------------------------------
__global__ __launch_bounds__(256, 3) void attn_kernel(
    const float* __restrict__ x,
    const float* __restrict__ Wq, const float* __restrict__ bq,
    const unsigned short* __restrict__ k_ws,
    const unsigned short* __restrict__ vt_ws,
    float* __restrict__ out)
{
    __shared__ unsigned short Ks[64 * 72];       // [key][e]
    __shared__ unsigned short Vt[64 * 72];       // [e][key]

    const int blk = blockIdx.x;    // 768 = 8 XCD * 12 bh * 8 qt
    const int xcd = blk & 7;
    const int idx = blk >> 3;      // 0..95
    const int bh  = xcd * 12 + (idx % 12);
    const int qt  = idx / 12;      // 0..7 (128-query tiles)
    const int t    = threadIdx.x;
    const int w    = t >> 6;
    const int lane = t & 63;
    const int l    = lane & 15;
    const int quad = lane >> 4;
    const int sr   = t >> 2;
    const int sc0  = (t & 3) * 16;

    const int b = bh / Hn, h = bh % Hn;
    const size_t base  = (size_t)bh * Sn * 64;   // k_ws [bh][s][e]
    const size_t vbase = (size_t)bh * 64 * Sn;   // vt_ws [bh][e][s]

    // ---- Q-projection prologue: 32 queries per wave, all in-register ----
    bf16x8 qf[2][2];
    {
        bf16x8 xq[2][2];
        #pragma unroll
        for (int st = 0; st < 2; st++) {
            const float* xp = x + ((size_t)(b * Sn + qt * 128 + w * 32 + st * 16 + l) * Dn
                                   + h * 64 + quad * 8);
            #pragma unroll
            for (int kc = 0; kc < 2; kc++) {
                float4 v0 = *(const float4*)(xp + kc * 32);
                float4 v1 = *(const float4*)(xp + kc * 32 + 4);
                unsigned int tmp[4] = {pk2bf(v0.x, v0.y), pk2bf(v0.z, v0.w),
                                       pk2bf(v1.x, v1.y), pk2bf(v1.z, v1.w)};
                xq[st][kc] = *(bf16x8*)tmp;
            }
        }
        unsigned qq[2][4][2];   // [st][nt][m] packed e-pairs (e = 16nt+4q+2m)
        #pragma unroll
        for (int nt = 0; nt < 4; nt++) {
            bf16x8 wa0 = wfrag(Wq + (size_t)h * 4096, nt * 16 + l, 0, quad, SQC);
            bf16x8 wa1 = wfrag(Wq + (size_t)h * 4096, nt * 16 + l, 1, quad, SQC);
            float4 bqv = *(const float4*)(bq + h * 64 + nt * 16 + quad * 4);
            #pragma unroll
            for (int st = 0; st < 2; st++) {
                f32x4 acc = (f32x4){bqv.x * SQC, bqv.y * SQC, bqv.z * SQC, bqv.w * SQC};
                acc = __builtin_amdgcn_mfma_f32_16x16x32_bf16(wa0, xq[st][0], acc, 0, 0, 0);
                acc = __builtin_amdgcn_mfma_f32_16x16x32_bf16(wa1, xq[st][1], acc, 0, 0, 0);
                qq[st][nt][0] = pk2bf(acc[0], acc[1]);
                qq[st][nt][1] = pk2bf(acc[2], acc[3]);
            }
        }
        #pragma unroll
        for (int st = 0; st < 2; st++)
            #pragma unroll
            for (int kc = 0; kc < 2; kc++) {
                unsigned t0 = qq[st][2 * kc][0], u0 = qq[st][2 * kc + 1][0];
                unsigned t1 = qq[st][2 * kc][1], u1 = qq[st][2 * kc + 1][1];
                quad_net(t0, u0, quad);
                quad_net(t1, u1, quad);
                unsigned tmp[4] = {t0, t1, u0, u1};
                qf[st][kc] = *(bf16x8*)tmp;
            }
    }

    f32x4 Oa[2][4];   // O^T: [st][e-strip nt]; row e=4*quad+r, col query=l
    #pragma unroll
    for (int st = 0; st < 2; st++)
        #pragma unroll
        for (int nt = 0; nt < 4; nt++) Oa[st][nt] = (f32x4){0.f, 0.f, 0.f, 0.f};
    float ps[2] = {0.f, 0.f};

    // ---- register prefetch of tile 0 ----
    uint4 kpre0, kpre1, vpre0, vpre1;
    {
        const unsigned short* kp = k_ws + base + (size_t)sr * 64 + sc0;
        kpre0 = *(const uint4*)kp;
        kpre1 = *(const uint4*)(kp + 8);
        const unsigned short* vp = vt_ws + vbase + (size_t)sr * Sn + sc0;
        vpre0 = *(const uint4*)vp;
        vpre1 = *(const uint4*)(vp + 8);
    }

    for (int kt = 0; kt < 16; kt++) {
        __syncthreads();   // prev-iter Ks/Vt readers done
        {   // commit prefetched tile kt to LDS
            *(uint4*)&Ks[sr * 72 + sc0]     = kpre0;
            *(uint4*)&Ks[sr * 72 + sc0 + 8] = kpre1;
            *(uint4*)&Vt[sr * 72 + sc0]     = vpre0;
            *(uint4*)&Vt[sr * 72 + sc0 + 8] = vpre1;
        }
        __syncthreads();   // Ks/Vt ready

        if (kt + 1 < 16) {  // issue tile kt+1 loads; complete during compute
            const unsigned short* kp = k_ws + base + (size_t)((kt + 1) * 64 + sr) * 64 + sc0;
            kpre0 = *(const uint4*)kp;
            kpre1 = *(const uint4*)(kp + 8);
            const unsigned short* vp = vt_ws + vbase + (size_t)sr * Sn + (kt + 1) * 64 + sc0;
            vpre0 = *(const uint4*)vp;
            vpre1 = *(const uint4*)(vp + 8);
        }

        // ---- S^T per key-strip nt: A = K rows, B = Q; exp2 + pack ----
        unsigned pp[2][4][2];  // [st][nt][m] packed P pairs (keys 16nt+4q+2m)
        #pragma unroll
        for (int nt = 0; nt < 4; nt++) {
            bf16x8 kf0 = *(bf16x8*)&Ks[(nt * 16 + l) * 72 + quad * 8];
            bf16x8 kf1 = *(bf16x8*)&Ks[(nt * 16 + l) * 72 + 32 + quad * 8];
            #pragma unroll
            for (int st = 0; st < 2; st++) {
                f32x4 s = (f32x4){0.f, 0.f, 0.f, 0.f};
                s = __builtin_amdgcn_mfma_f32_16x16x32_bf16(kf0, qf[st][0], s, 0, 0, 0);
                s = __builtin_amdgcn_mfma_f32_16x16x32_bf16(kf1, qf[st][1], s, 0, 0, 0);
                float p0 = exp2f(s[0]), p1 = exp2f(s[1]);
                float p2 = exp2f(s[2]), p3 = exp2f(s[3]);
                ps[st] += (p0 + p1) + (p2 + p3);
                pp[st][nt][0] = pk2bf(p0, p1);
                pp[st][nt][1] = pk2bf(p2, p3);
            }
        }

        // ---- quad_net: pp -> PV B-fragments (replaces P LDS roundtrip) ----
        bf16x8 pb[2][2];
        #pragma unroll
        for (int st = 0; st < 2; st++)
            #pragma unroll
            for (int kc = 0; kc < 2; kc++) {
                unsigned t0 = pp[st][2 * kc][0], u0 = pp[st][2 * kc + 1][0];
                unsigned t1 = pp[st][2 * kc][1], u1 = pp[st][2 * kc + 1][1];
                quad_net(t0, u0, quad);
                quad_net(t1, u1, quad);
                unsigned tmp[4] = {t0, t1, u0, u1};
                pb[st][kc] = *(bf16x8*)tmp;
            }

        // ---- O^T += V^T.P : A = V^T rows (vf), B = P (pb) ----
        #pragma unroll
        for (int nt = 0; nt < 4; nt++) {
            bf16x8 vf0 = *(bf16x8*)&Vt[(nt * 16 + l) * 72 + quad * 8];
            bf16x8 vf1 = *(bf16x8*)&Vt[(nt * 16 + l) * 72 + 32 + quad * 8];
            #pragma unroll
            for (int st = 0; st < 2; st++) {
                Oa[st][nt] = __builtin_amdgcn_mfma_f32_16x16x32_bf16(vf0, pb[st][0], Oa[st][nt], 0, 0, 0);
                Oa[st][nt] = __builtin_amdgcn_mfma_f32_16x16x32_bf16(vf1, pb[st][1], Oa[st][nt], 0, 0, 0);
            }
        }
    }

    // fold partial sums across the 4 quads; per-lane normalizer (query = l)
    #pragma unroll
    for (int st = 0; st < 2; st++) {
        ps[st] += __shfl_xor(ps[st], 16, 64);
        ps[st] += __shfl_xor(ps[st], 32, 64);
        const float inv = 1.0f / ps[st];
        const int srow = qt * 128 + w * 32 + st * 16 + l;
        #pragma unroll
        for (int nt = 0; nt < 4; nt++) {
            float4 o = make_float4(Oa[st][nt][0] * inv, Oa[st][nt][1] * inv,
                                   Oa[st][nt][2] * inv, Oa[st][nt][3] * inv);
            *(float4*)&out[(size_t)(b * Sn + srow) * Dn + h * 64 + nt * 16 + quad * 4] = o;
        }
    }
}

// ---------------------------------------------------------------------------
extern "C" void kernel_launch(void* const* d_in, const int* in_sizes, int n_in,
                              void* d_out, int out_size, void* d_ws, size_t ws_size,
                              hipStream_t stream) {
    const float* x  = (const float*)d_in[0];
    const float* Wq = (const float*)d_in[1];
    const float* bq = (const float*)d_in[2];
    const float* Wk = (const float*)d_in[3];
    const float* bk = (const float*)d_in[4];
    const float* Wv = (const float*)d_in[5];
    const float* bv = (const float*)d_in[6];
    float* out = (float*)d_out;

    unsigned short* k_ws  = (unsigned short*)d_ws;
    unsigned short* vt_ws = k_ws + QKV_ELEMS;

    hipLaunchKernelGGL(proj_kernel, dim3(Bn * Hn * 16), dim3(256), 0, stream,
                       x, Wk, bk, Wv, bv, k_ws, vt_ws);
    hipLaunchKernelGGL(attn_kernel, dim3(Bn * Hn * 8), dim3(256), 0, stream,
                       x, Wq, bq, k_ws, vt_ws, out);
}